// Round 10
// baseline (212.505 us; speedup 1.0000x reference)
//
#include <hip/hip_runtime.h>
#include <math.h>

typedef __bf16 bf16_t;
typedef __bf16 bf16x8 __attribute__((ext_vector_type(8)));
typedef float f32x4 __attribute__((ext_vector_type(4)));
typedef float f32x2 __attribute__((ext_vector_type(2)));

#define B_INS 8192
#define N_INS 16384
#define D 128
#define BP 256
#define P 256
#define NP 512

// exp(l-10) with l = dot*10  ==  exp2(dot*C1 - C1), C1 = 10*log2(e)
#define C1_CONST 14.426950408889634f

// ---------------- workspace layout (floats) ----------------
// Atomic-free: gram writes per-pair partials with unique owners; fin reduces.
// acc[0]=ins sum, acc[1]=patch sum, acc[2]=n_valid, acc[3]=ticket
#define WS_ACC 0
#define WS_POS 8                               // ins pos logits [16384]
#define WS_PPOS (WS_POS + N_INS)               // patch pos logits [BP*NP]
#define NPAIRI 8128                            // 128*127/2 pairs (C>R), tri = C(C-1)/2+R
#define WS_CI (WS_PPOS + BP * NP)              // colPartI [NPAIRI][2(rh)][128]
#define WS_RI (WS_CI + NPAIRI * 256)           // rowPartI [1088 chunks][2(ch)][128]
#define WS_CP (WS_RI + 1088 * 256)             // colPartP [BP][6 tri][2(rh)][128]
#define WS_RP (WS_CP + BP * 6 * 256)           // rowPartP [BP*4][2(ch)][128]
#define WS_END (WS_RP + 1024 * 256)
#define EMB_I_BYTE ((((WS_END) * 4 + 15) / 16) * 16)
#define EMB_P_BYTE (EMB_I_BYTE + N_INS * D * 2)

// Panel layout: global row i, k -> panel p=i>>7, r=i&127, g=k>>3, j=k&7
// elem offset = (p<<14) + (g<<10) + (r<<3) + j. One panel = 32 KB contiguous.

// grid partitioning
#define NB_NORMI 128        // one block per ins panel
#define NB_NORMP 2048
#define NB_PREP (NB_NORMI + NB_NORMP + 1)   // +1 block zeroes acc
#define NB_INS 1088         // ins: (R, chunk of 8 C-panels), octet decode
#define NB_PATCHB 1024      // patch: (batch, R-panel), C = R..3
#define NB_GRAM (NB_INS + NB_PATCHB)
#define NB_FIN (128 + 256)  // 128 ins-panel blocks + 256 batch blocks

// ---------------- A-fragment register load (from L2, panel layout) -----------
__device__ __forceinline__ void load_afrags(const bf16_t* __restrict__ abase,
                                            int rh, int tx, int q, bf16x8 af[4][4]) {
    const bf16_t* a = abase + ((rh * 64 + tx) << 3);
#pragma unroll
    for (int rt = 0; rt < 4; rt++)
#pragma unroll
        for (int ks = 0; ks < 4; ks++)
            af[rt][ks] = *(const bf16x8*)(a + (((ks << 2) + q) << 10) + (rt << 7));
}

// ================= kernel 1: prep (norms + acc zero) =================
__global__ __launch_bounds__(256) void prep_k(const float* __restrict__ v1i,
                                              const float* __restrict__ v2i,
                                              const float* __restrict__ v1p,
                                              const float* __restrict__ v2p,
                                              bf16_t* __restrict__ embI,
                                              bf16_t* __restrict__ embP,
                                              float* __restrict__ ws) {
    __shared__ float L[128][65];
    __shared__ float ps[4][64];
    __shared__ float invs[128];
    int bx = blockIdx.x;
    int t = threadIdx.x;
    if (bx < NB_NORMI) {
        // one block per 128-row ins panel; panels 0..63 from v1i, 64..127 from v2i
        int p = bx;
        const float* srcP = (p < 64) ? (v1i + (size_t)p * 128 * D)
                                     : (v2i + (size_t)(p - 64) * 128 * D);
        // phase 1: per-row inv norms (2 threads per row)
        {
            int r = t >> 1, h = t & 1;
            const float* row = srcP + (size_t)r * D + h * 64;
            float ss = 0.f;
#pragma unroll
            for (int j = 0; j < 16; j++) {
                float4 v = *(const float4*)(row + j * 4);
                ss += v.x * v.x + v.y * v.y + v.z * v.z + v.w * v.w;
            }
            ss += __shfl_xor(ss, 1, 64);
            if (h == 0) invs[r] = 1.0f / fmaxf(sqrtf(ss), 1e-12f);
        }
        __syncthreads();
        // phase 2: re-read (L2-hot), scale, 16B coalesced panel-layout stores
#pragma unroll
        for (int it = 0; it < 8; it++) {
            int idx = it * 256 + t;
            int r = idx & 127, g = idx >> 7;
            const float* src8 = srcP + (size_t)r * D + g * 8;
            float4 a = *(const float4*)(src8);
            float4 b = *(const float4*)(src8 + 4);
            float inv = invs[r];
            bf16x8 v;
            v[0] = (bf16_t)(a.x * inv); v[1] = (bf16_t)(a.y * inv);
            v[2] = (bf16_t)(a.z * inv); v[3] = (bf16_t)(a.w * inv);
            v[4] = (bf16_t)(b.x * inv); v[5] = (bf16_t)(b.y * inv);
            v[6] = (bf16_t)(b.z * inv); v[7] = (bf16_t)(b.w * inv);
            *(bf16x8*)(embI + ((size_t)p << 14) + (g << 10) + (r << 3)) = v;
        }
    } else if (bx < NB_NORMI + NB_NORMP) {
        int bx2 = bx - NB_NORMI;
        int b = bx2 >> 3, h = (bx2 >> 2) & 1, chunk = bx2 & 3;
        int i0 = chunk * 64;
        const float* src = ((h == 0) ? v1p : v2p) + (size_t)b * D * P;
#pragma unroll
        for (int it = 0; it < 8; it++) {
            int fi = it * 256 + t;
            int d = fi >> 4, c4 = fi & 15;
            float4 v = *(const float4*)(src + (size_t)d * P + i0 + c4 * 4);
            L[d][c4 * 4 + 0] = v.x;
            L[d][c4 * 4 + 1] = v.y;
            L[d][c4 * 4 + 2] = v.z;
            L[d][c4 * 4 + 3] = v.w;
        }
        __syncthreads();
        {
            int col = t & 63, part = t >> 6;
            float ss = 0.f;
#pragma unroll 8
            for (int d = part * 32; d < part * 32 + 32; d++) { float x = L[d][col]; ss += x * x; }
            ps[part][col] = ss;
        }
        __syncthreads();
        if (t < 64) {
            float n2 = ps[0][t] + ps[1][t] + ps[2][t] + ps[3][t];
            invs[t] = 1.0f / fmaxf(sqrtf(n2), 1e-12f);
        }
        __syncthreads();
        // 16B coalesced panel-layout stores: lanes sweep ic (contiguous runs)
#pragma unroll
        for (int it = 0; it < 4; it++) {
            int idx = it * 256 + t;
            int ic = idx & 63, g = idx >> 6;
            float inv = invs[ic];
            bf16x8 v;
#pragma unroll
            for (int j = 0; j < 8; j++) v[j] = (bf16_t)(L[g * 8 + j][ic] * inv);
            int iLoc = h * P + i0 + ic;
            *(bf16x8*)(embP + ((size_t)b << 16) + ((size_t)(iLoc >> 7) << 14) +
                       (g << 10) + ((iLoc & 127) << 3)) = v;
        }
    } else {
        if (t < 8) ws[t] = 0.f;   // acc + ticket
    }
}

// ================= kernel 2: unified Gram (ins + patch), atomic-free ========
// LDS-FREE, BARRIER-FREE k-loop: B fragments loaded per-lane directly from
// global (panels are L2-resident: embI 4MB/XCD-L2, embP 64KB/batch; 346 MB
// total L2 reads over the kernel ~ 6 TB/s << 34.5 TB/s ceiling). This is the
// round-1 structure minus its two proven poisons (contended atomics in the
// vmcnt FIFO; (256,3) VGPR cap). Waves fully dephased: exp2-VALU, MFMA, and
// load latency overlap across waves with no per-step lockstep drain.
// LDS=0 + natural VGPR (~116-130) -> up to 4 waves/SIMD.
__global__ __launch_bounds__(256) void gram_k(const bf16_t* __restrict__ embI,
                                              const bf16_t* __restrict__ embP,
                                              float* __restrict__ pos,
                                              float* __restrict__ posp,
                                              float* __restrict__ colI,
                                              float* __restrict__ rowI,
                                              float* __restrict__ colP,
                                              float* __restrict__ rowP) {
    int t = threadIdx.x, w = t >> 6, lane = t & 63;
    int tx = lane & 15, q = lane >> 4;
    int rh = w & 1, ch = w >> 1;
    int bx = blockIdx.x;

    const bf16_t *Abase, *Bbase;
    float *posArr, *colArr, *rowDst;
    int R, c0, n, diagC, posC;
    if (bx < NB_INS) {
        // octet decode: R in octet k has (16-k) chunks of 8
        int bid = bx, k = 0, cum = 0;
        while (bid >= cum + 8 * (16 - k)) { cum += 8 * (16 - k); k++; }
        int rem = bid - cum, cc = 16 - k;
        R = 8 * k + rem / cc;
        int ci = rem - (rem / cc) * cc;
        c0 = R + ci * 8;
        n = min(8, 128 - c0);
        Abase = embI + ((size_t)R << 14);
        Bbase = embI;
        posArr = pos;
        colArr = colI + (size_t)R * 256;               // + tri(C)*256 added per C
        rowDst = rowI + (size_t)(R * 16 + ci) * 256;   // [ch][128]
        diagC = R; posC = R + 64;
    } else {
        int pi = bx - NB_INS;
        int b = pi >> 2; R = pi & 3;
        c0 = R; n = 4 - R;
        const bf16_t* base = embP + ((size_t)b << 16);
        Abase = base + ((size_t)R << 14);
        Bbase = base;
        posArr = posp + (size_t)b * NP;
        colArr = colP + (size_t)(b * 6 + R) * 256;
        rowDst = rowP + (size_t)((b << 2) + R) * 256;
        diagC = R; posC = R + 2;            // pos pairs (0,2),(1,3); R>=2 has none
    }
    int rowBase = R * 128;

    bf16x8 af[4][4];
    load_afrags(Abase, rh, tx, q, af);

    f32x2 rowS2[8];
#pragma unroll
    for (int i = 0; i < 8; i++) rowS2[i] = (f32x2){0.f, 0.f};

    // per-lane B base: elem off within panel = ((ks*4+q)<<10) + ((ch*64+nt*16+tx)<<3)
    const bf16_t* bcol = Bbase + ((size_t)q << 10) + ((ch * 64 + tx) << 3);

    for (int ti = 0; ti < n; ti++) {
        int C = c0 + ti;
        bool isDiag = (C == diagC), isPos = (C == posC);
        int colBase = C * 128;
        const bf16_t* pb = bcol + ((size_t)C << 14);

        float colS[4];
#pragma unroll
        for (int nt = 0; nt < 4; nt++) {
            bf16x8 bf[4];
#pragma unroll
            for (int ks = 0; ks < 4; ks++)
                bf[ks] = *(const bf16x8*)(pb + (ks << 12) + (nt << 7));
            f32x4 acc[4];
#pragma unroll
            for (int rt = 0; rt < 4; rt++) acc[rt] = (f32x4){0.f, 0.f, 0.f, 0.f};
            __builtin_amdgcn_s_setprio(1);
#pragma unroll
            for (int ks = 0; ks < 4; ks++)
#pragma unroll
                for (int rt = 0; rt < 4; rt++)
                    acc[rt] = __builtin_amdgcn_mfma_f32_16x16x32_bf16(
                        af[rt][ks], bf[ks], acc[rt], 0, 0, 0);
            __builtin_amdgcn_s_setprio(0);

            // packed epilogue: f32x2 lanes -> v_pk_fma/v_pk_add
            f32x2 cs = (f32x2){0.f, 0.f};
#pragma unroll
            for (int rt = 0; rt < 4; rt++) {
                f32x2 l0 = {acc[rt][0], acc[rt][1]};
                f32x2 l1 = {acc[rt][2], acc[rt][3]};
                l0 = l0 * C1_CONST - C1_CONST;
                l1 = l1 * C1_CONST - C1_CONST;
                f32x2 e0 = {__builtin_amdgcn_exp2f(l0.x), __builtin_amdgcn_exp2f(l0.y)};
                f32x2 e1 = {__builtin_amdgcn_exp2f(l1.x), __builtin_amdgcn_exp2f(l1.y)};
                if (isDiag) {
                    int inRow = rh * 64 + rt * 16 + q * 4;
                    int inCol = ch * 64 + nt * 16 + tx;
                    if (inRow + 0 == inCol) e0.x = 0.f;
                    if (inRow + 1 == inCol) e0.y = 0.f;
                    if (inRow + 2 == inCol) e1.x = 0.f;
                    if (inRow + 3 == inCol) e1.y = 0.f;
                }
                rowS2[rt * 2] += e0;
                rowS2[rt * 2 + 1] += e1;
                cs += e0 + e1;
            }
            colS[nt] = cs.x + cs.y;

            if (isPos && ch == rh) {
                int reg = tx - q * 4;
                if (reg >= 0 && reg < 4) {
                    float pl = acc[nt][reg] * 10.0f;   // rt==nt diagonal fragment
                    // each target row has exactly one writer -> plain stores
                    posArr[rowBase + rh * 64 + nt * 16 + tx] = pl;
                    posArr[colBase + rh * 64 + nt * 16 + tx] = pl;
                }
            }
        }
        if (!isDiag) {
#pragma unroll
            for (int i = 0; i < 4; i++) {
                colS[i] += __shfl_xor(colS[i], 16, 64);
                colS[i] += __shfl_xor(colS[i], 32, 64);
            }
            if (q == 0) {
                // slot (tri(C,R), rh): unique (rh,col) writer per pair
                float* cdst = colArr + (size_t)(C * (C - 1) / 2) * 256 + rh * 128;
#pragma unroll
                for (int nt = 0; nt < 4; nt++)
                    cdst[ch * 64 + nt * 16 + tx] = colS[nt];
            }
        }
    }
    // flush rowS: reduce over 16 tx lanes, plain store into [chunk][ch][row]
    float* rowS = (float*)rowS2;   // [rt*4 + reg]
#pragma unroll
    for (int off = 1; off <= 8; off <<= 1)
#pragma unroll
        for (int i = 0; i < 16; i++) rowS[i] += __shfl_xor(rowS[i], off, 16);
    if (tx == 0) {
#pragma unroll
        for (int rt = 0; rt < 4; rt++)
#pragma unroll
            for (int reg = 0; reg < 4; reg++)
                rowDst[ch * 128 + rh * 64 + rt * 16 + q * 4 + reg] =
                    rowS[rt * 4 + reg];
    }
}

// ================= kernel 3: finalize (reduce partials, 512t + term-split) ====
__global__ __launch_bounds__(512) void fin_k(const float* __restrict__ pos,
                                             const float* __restrict__ posp,
                                             const float* __restrict__ colI,
                                             const float* __restrict__ rowI,
                                             const float* __restrict__ colP,
                                             const float* __restrict__ rowP,
                                             const int* __restrict__ c1,
                                             const int* __restrict__ c2,
                                             float* __restrict__ acc,
                                             float* __restrict__ out) {
    int bx = blockIdx.x, t = threadIdx.x;
    int lane = t & 63, w = t >> 6;
    float va = 0.f, nv = 0.f;
    __shared__ float part[2][2][128];
    if (bx < 128) {
        // ins panel p: S[p*128+r] = sum_ci rowI[p*16+ci][s][r] + sum_{R<p} colI[tri(p,R)][s][r]
        int p = 127 - bx;                 // heaviest (largest p) panels first
        int u = t >> 8, half = (t >> 7) & 1, r = t & 127;
        int cc = 16 - (p >> 3);
        float s0 = 0.f, s1 = 0.f, s2 = 0.f, s3 = 0.f;
        const float* RIp = rowI + (size_t)(p * 16) * 256 + half * 128 + r;
        int ci = u;
        for (; ci + 6 < cc; ci += 8) {
            s0 += RIp[ci * 256];       s1 += RIp[(ci + 2) * 256];
            s2 += RIp[(ci + 4) * 256]; s3 += RIp[(ci + 6) * 256];
        }
        for (; ci < cc; ci += 2) s0 += RIp[ci * 256];
        const float* CIp = colI + (size_t)(p * (p - 1) / 2) * 256 + half * 128 + r;
        int Rq = u;
        for (; Rq + 6 < p; Rq += 8) {
            s0 += CIp[Rq * 256];       s1 += CIp[(Rq + 2) * 256];
            s2 += CIp[(Rq + 4) * 256]; s3 += CIp[(Rq + 6) * 256];
        }
        for (; Rq < p; Rq += 2) s0 += CIp[Rq * 256];
        part[u][half][r] = (s0 + s1) + (s2 + s3);
        __syncthreads();
        if (t < 128) {
            float S = (part[0][0][t] + part[0][1][t]) +
                      (part[1][0][t] + part[1][1][t]);
            va = __logf(S) + 10.0f - pos[p * 128 + t];
        }
    } else {
        // patch batch b: 512 rows, one per thread
        int b = bx - 128;
        int idx = t;                      // 0..511
        int p = idx >> 7, r = idx & 127;
        const float* RPp = rowP + (size_t)((b << 2) + p) * 256 + r;
        float s = RPp[0] + RPp[128];
        const float* CPp = colP + (size_t)(b * 6 + p * (p - 1) / 2) * 256 + r;
        for (int Rq = 0; Rq < p; Rq++) s += CPp[Rq * 256] + CPp[Rq * 256 + 128];
        int cnt = (idx < P) ? c1[b * P + idx] : c2[b * P + idx - P];
        if (cnt != 0) {
            va = __logf(s) + 10.0f - posp[b * NP + idx];
            nv = 1.0f;
        }
    }
#pragma unroll
    for (int off = 32; off >= 1; off >>= 1) {
        va += __shfl_down(va, off, 64);
        nv += __shfl_down(nv, off, 64);
    }
    __shared__ float psum[8], pn[8];
    if (lane == 0) { psum[w] = va; pn[w] = nv; }
    __syncthreads();
    if (t == 0) {
        float sv = 0.f, sn = 0.f;
#pragma unroll
        for (int i = 0; i < 8; i++) { sv += psum[i]; sn += pn[i]; }
        if (bx < 128) {
            atomicAdd(&acc[0], sv);
        } else {
            atomicAdd(&acc[1], sv);
            atomicAdd(&acc[2], sn);
        }
        __threadfence();
        unsigned old = atomicAdd((unsigned*)&acc[3], 1u);
        if (old == NB_FIN - 1) {
            float a0 = atomicAdd(&acc[0], 0.0f);
            float a1 = atomicAdd(&acc[1], 0.0f);
            float a2 = atomicAdd(&acc[2], 0.0f);
            out[0] = a0 * (1.0f / (float)N_INS) + a1 / a2;
        }
    }
}

// ---------------- launch ----------------
extern "C" void kernel_launch(void* const* d_in, const int* in_sizes, int n_in,
                              void* d_out, int out_size, void* d_ws, size_t ws_size,
                              hipStream_t stream) {
    const float* v1i = (const float*)d_in[0];
    const float* v2i = (const float*)d_in[1];
    const float* v1p = (const float*)d_in[2];
    const float* v2p = (const float*)d_in[3];
    const int* c1 = (const int*)d_in[4];
    const int* c2 = (const int*)d_in[5];
    float* ws = (float*)d_ws;
    float* out = (float*)d_out;
    bf16_t* embI = (bf16_t*)((char*)d_ws + EMB_I_BYTE);
    bf16_t* embP = (bf16_t*)((char*)d_ws + EMB_P_BYTE);

    prep_k<<<NB_PREP, 256, 0, stream>>>(v1i, v2i, v1p, v2p, embI, embP, ws);
    gram_k<<<NB_GRAM, 256, 0, stream>>>(embI, embP, ws + WS_POS, ws + WS_PPOS,
                                        ws + WS_CI, ws + WS_RI,
                                        ws + WS_CP, ws + WS_RP);
    fin_k<<<NB_FIN, 512, 0, stream>>>(ws + WS_POS, ws + WS_PPOS, ws + WS_CI,
                                      ws + WS_RI, ws + WS_CP, ws + WS_RP,
                                      c1, c2, ws + WS_ACC, out);
}

// Round 11
// 202.654 us; speedup vs baseline: 1.0486x; 1.0486x over previous
//
#include <hip/hip_runtime.h>
#include <math.h>

typedef __bf16 bf16_t;
typedef __bf16 bf16x8 __attribute__((ext_vector_type(8)));
typedef float f32x4 __attribute__((ext_vector_type(4)));
typedef float f32x2 __attribute__((ext_vector_type(2)));

#define B_INS 8192
#define N_INS 16384
#define D 128
#define BP 256
#define P 256
#define NP 512

// exp(l-10) with l = dot*10  ==  exp2(dot*C1 - C1), C1 = 10*log2(e).
// Embeddings are pre-scaled by sqrt(C1) in prep and the MFMA accumulator is
// initialized to -C1, so MFMA emits exp2's argument directly (no epilogue fma).
#define C1_CONST 14.426950408889634f
#define SQRT_C1 3.798283f
#define LN2_CONST 0.69314718056f

// ---------------- workspace layout (floats) ----------------
// Atomic-free: gram writes per-pair partials with unique owners; fin reduces.
// acc[0]=ins sum, acc[1]=patch sum, acc[2]=n_valid, acc[3]=ticket
#define WS_ACC 0
#define WS_POS 8                               // ins pos logits [16384]
#define WS_PPOS (WS_POS + N_INS)               // patch pos logits [BP*NP]
#define NPAIRI 8128                            // 128*127/2 pairs (C>R), tri = C(C-1)/2+R
#define WS_CI (WS_PPOS + BP * NP)              // colPartI [NPAIRI][2(rh)][128]
#define WS_RI (WS_CI + NPAIRI * 256)           // rowPartI [1088 chunks][2(ch)][128]
#define WS_CP (WS_RI + 1088 * 256)             // colPartP [BP][6 tri][2(rh)][128]
#define WS_RP (WS_CP + BP * 6 * 256)           // rowPartP [BP*4][2(ch)][128]
#define WS_END (WS_RP + 1024 * 256)
#define EMB_I_BYTE ((((WS_END) * 4 + 15) / 16) * 16)
#define EMB_P_BYTE (EMB_I_BYTE + N_INS * D * 2)

// Panel layout: global row i, k -> panel p=i>>7, r=i&127, g=k>>3, j=k&7
// elem offset = (p<<14) + (g<<10) + (r<<3) + j. One panel = 32 KB contiguous.

// grid partitioning
#define NB_NORMI 128        // one block per ins panel
#define NB_NORMP 2048
#define NB_PREP (NB_NORMI + NB_NORMP + 1)   // +1 block zeroes acc
#define NB_INS 1088         // ins: (R, chunk of 8 C-panels), octet decode
#define NB_PATCHB 1024      // patch: (batch, R-panel), C = R..3
#define NB_GRAM (NB_INS + NB_PATCHB)
#define NB_FIN (128 + 256)  // 128 ins-panel blocks + 256 batch blocks

// ---------------- staging: linear 32 KB panel copy (async, wave-uniform dst) ----
__device__ __forceinline__ void load_lds16(const bf16_t* g, bf16_t* l) {
    __builtin_amdgcn_global_load_lds(
        (const __attribute__((address_space(1))) void*)g,
        (__attribute__((address_space(3))) void*)l, 16, 0, 0);
}

__device__ __forceinline__ void stage_panel(const bf16_t* __restrict__ src,
                                            bf16_t* dst, int w, int lane) {
    const bf16_t* g = src + w * 4096 + lane * 8;
    bf16_t* d = dst + w * 4096;
#pragma unroll
    for (int it = 0; it < 8; it++)
        load_lds16(g + it * 512, d + it * 512);
}

// ---------------- A-fragment register load (from L2, panel layout) -----------
__device__ __forceinline__ void load_afrags(const bf16_t* __restrict__ abase,
                                            int rh, int tx, int q, bf16x8 af[4][4]) {
    const bf16_t* a = abase + ((rh * 64 + tx) << 3);
#pragma unroll
    for (int rt = 0; rt < 4; rt++)
#pragma unroll
        for (int ks = 0; ks < 4; ks++)
            af[rt][ks] = *(const bf16x8*)(a + (((ks << 2) + q) << 10) + (rt << 7));
}

// ================= kernel 1: prep (norms + acc zero) =================
// Embeddings stored pre-scaled by sqrt(C1): MFMA dot then equals C1*dot of
// unit vectors, feeding exp2 directly (see gram).
__global__ __launch_bounds__(256) void prep_k(const float* __restrict__ v1i,
                                              const float* __restrict__ v2i,
                                              const float* __restrict__ v1p,
                                              const float* __restrict__ v2p,
                                              bf16_t* __restrict__ embI,
                                              bf16_t* __restrict__ embP,
                                              float* __restrict__ ws) {
    __shared__ float L[128][65];
    __shared__ float ps[4][64];
    __shared__ float invs[128];
    int bx = blockIdx.x;
    int t = threadIdx.x;
    if (bx < NB_NORMI) {
        // one block per 128-row ins panel; panels 0..63 from v1i, 64..127 from v2i
        int p = bx;
        const float* srcP = (p < 64) ? (v1i + (size_t)p * 128 * D)
                                     : (v2i + (size_t)(p - 64) * 128 * D);
        // phase 1: per-row inv norms (2 threads per row)
        {
            int r = t >> 1, h = t & 1;
            const float* row = srcP + (size_t)r * D + h * 64;
            float ss = 0.f;
#pragma unroll
            for (int j = 0; j < 16; j++) {
                float4 v = *(const float4*)(row + j * 4);
                ss += v.x * v.x + v.y * v.y + v.z * v.z + v.w * v.w;
            }
            ss += __shfl_xor(ss, 1, 64);
            if (h == 0) invs[r] = SQRT_C1 / fmaxf(sqrtf(ss), 1e-12f);
        }
        __syncthreads();
        // phase 2: re-read (L2-hot), scale, 16B coalesced panel-layout stores
#pragma unroll
        for (int it = 0; it < 8; it++) {
            int idx = it * 256 + t;
            int r = idx & 127, g = idx >> 7;
            const float* src8 = srcP + (size_t)r * D + g * 8;
            float4 a = *(const float4*)(src8);
            float4 b = *(const float4*)(src8 + 4);
            float inv = invs[r];
            bf16x8 v;
            v[0] = (bf16_t)(a.x * inv); v[1] = (bf16_t)(a.y * inv);
            v[2] = (bf16_t)(a.z * inv); v[3] = (bf16_t)(a.w * inv);
            v[4] = (bf16_t)(b.x * inv); v[5] = (bf16_t)(b.y * inv);
            v[6] = (bf16_t)(b.z * inv); v[7] = (bf16_t)(b.w * inv);
            *(bf16x8*)(embI + ((size_t)p << 14) + (g << 10) + (r << 3)) = v;
        }
    } else if (bx < NB_NORMI + NB_NORMP) {
        int bx2 = bx - NB_NORMI;
        int b = bx2 >> 3, h = (bx2 >> 2) & 1, chunk = bx2 & 3;
        int i0 = chunk * 64;
        const float* src = ((h == 0) ? v1p : v2p) + (size_t)b * D * P;
#pragma unroll
        for (int it = 0; it < 8; it++) {
            int fi = it * 256 + t;
            int d = fi >> 4, c4 = fi & 15;
            float4 v = *(const float4*)(src + (size_t)d * P + i0 + c4 * 4);
            L[d][c4 * 4 + 0] = v.x;
            L[d][c4 * 4 + 1] = v.y;
            L[d][c4 * 4 + 2] = v.z;
            L[d][c4 * 4 + 3] = v.w;
        }
        __syncthreads();
        {
            int col = t & 63, part = t >> 6;
            float ss = 0.f;
#pragma unroll 8
            for (int d = part * 32; d < part * 32 + 32; d++) { float x = L[d][col]; ss += x * x; }
            ps[part][col] = ss;
        }
        __syncthreads();
        if (t < 64) {
            float n2 = ps[0][t] + ps[1][t] + ps[2][t] + ps[3][t];
            invs[t] = SQRT_C1 / fmaxf(sqrtf(n2), 1e-12f);
        }
        __syncthreads();
        // 16B coalesced panel-layout stores: lanes sweep ic (contiguous runs)
#pragma unroll
        for (int it = 0; it < 4; it++) {
            int idx = it * 256 + t;
            int ic = idx & 63, g = idx >> 6;
            float inv = invs[ic];
            bf16x8 v;
#pragma unroll
            for (int j = 0; j < 8; j++) v[j] = (bf16_t)(L[g * 8 + j][ic] * inv);
            int iLoc = h * P + i0 + ic;
            *(bf16x8*)(embP + ((size_t)b << 16) + ((size_t)(iLoc >> 7) << 14) +
                       (g << 10) + ((iLoc & 127) << 3)) = v;
        }
    } else {
        if (t < 8) ws[t] = 0.f;   // acc + ticket
    }
}

// ================= kernel 2: unified Gram (ins + patch), atomic-free ========
// r8 staging/store structure (83.0 us) + two within-wave serial-chain cuts:
// (1) acc init = -C1 with sqrt(C1)-scaled emb -> MFMA output IS exp2's
//     argument; epilogue pk_fma eliminated.
// (2) 2-stage software pipeline over nt (static accA/accB, bfA/bfB names):
//     nt+1's ds_read+MFMA cluster issues BEFORE nt's register-only epilogue,
//     so exp2/add VALU overlaps the matrix pipe within one wave.
__global__ __launch_bounds__(256) void gram_k(const bf16_t* __restrict__ embI,
                                              const bf16_t* __restrict__ embP,
                                              float* __restrict__ pos,
                                              float* __restrict__ posp,
                                              float* __restrict__ colI,
                                              float* __restrict__ rowI,
                                              float* __restrict__ colP,
                                              float* __restrict__ rowP) {
    __shared__ __align__(16) bf16_t shB[2][16384];
    int t = threadIdx.x, w = t >> 6, lane = t & 63;
    int tx = lane & 15, q = lane >> 4;
    int rh = w & 1, ch = w >> 1;
    int bx = blockIdx.x;

    const bf16_t *Abase, *Bbase;
    float *posArr, *colArr, *rowDst;
    int R, c0, n, diagC, posC;
    if (bx < NB_INS) {
        // octet decode: R in octet k has (16-k) chunks of 8
        int bid = bx, k = 0, cum = 0;
        while (bid >= cum + 8 * (16 - k)) { cum += 8 * (16 - k); k++; }
        int rem = bid - cum, cc = 16 - k;
        R = 8 * k + rem / cc;
        int ci = rem - (rem / cc) * cc;
        c0 = R + ci * 8;
        n = min(8, 128 - c0);
        Abase = embI + ((size_t)R << 14);
        Bbase = embI;
        posArr = pos;
        colArr = colI + (size_t)R * 256;               // + tri(C)*256 added per C
        rowDst = rowI + (size_t)(R * 16 + ci) * 256;   // [ch][128]
        diagC = R; posC = R + 64;
    } else {
        int pi = bx - NB_INS;
        int b = pi >> 2; R = pi & 3;
        c0 = R; n = 4 - R;
        const bf16_t* base = embP + ((size_t)b << 16);
        Abase = base + ((size_t)R << 14);
        Bbase = base;
        posArr = posp + (size_t)b * NP;
        colArr = colP + (size_t)(b * 6 + R) * 256;
        rowDst = rowP + (size_t)((b << 2) + R) * 256;
        diagC = R; posC = R + 2;            // pos pairs (0,2),(1,3); R>=2 has none
    }
    int rowBase = R * 128;

    bf16x8 af[4][4];
    load_afrags(Abase, rh, tx, q, af);

    f32x2 rowS2[8];
#pragma unroll
    for (int i = 0; i < 8; i++) rowS2[i] = (f32x2){0.f, 0.f};

#define LOADBF(BF, NT)                                                        \
    _Pragma("unroll") for (int ks = 0; ks < 4; ks++)                          \
        BF[ks] = *(const bf16x8*)(sb + (((ks << 2) + q) << 10) +              \
                                  ((ch * 64 + (NT) * 16 + tx) << 3));

#define MFMAS(ACC, BF)                                                        \
    _Pragma("unroll") for (int rt = 0; rt < 4; rt++)                          \
        ACC[rt] = (f32x4){-C1_CONST, -C1_CONST, -C1_CONST, -C1_CONST};        \
    __builtin_amdgcn_s_setprio(1);                                            \
    _Pragma("unroll") for (int ks = 0; ks < 4; ks++)                          \
        _Pragma("unroll") for (int rt = 0; rt < 4; rt++)                      \
            ACC[rt] = __builtin_amdgcn_mfma_f32_16x16x32_bf16(                \
                af[rt][ks], BF[ks], ACC[rt], 0, 0, 0);                        \
    __builtin_amdgcn_s_setprio(0);

#define EPI(NT, ACC) {                                                        \
    f32x2 cs = (f32x2){0.f, 0.f};                                             \
    _Pragma("unroll") for (int rt = 0; rt < 4; rt++) {                        \
        f32x2 e0 = {__builtin_amdgcn_exp2f(ACC[rt][0]),                       \
                    __builtin_amdgcn_exp2f(ACC[rt][1])};                      \
        f32x2 e1 = {__builtin_amdgcn_exp2f(ACC[rt][2]),                       \
                    __builtin_amdgcn_exp2f(ACC[rt][3])};                      \
        if (isDiag) {                                                         \
            int inRow = rh * 64 + rt * 16 + q * 4;                            \
            int inCol = ch * 64 + (NT) * 16 + tx;                             \
            if (inRow + 0 == inCol) e0.x = 0.f;                               \
            if (inRow + 1 == inCol) e0.y = 0.f;                               \
            if (inRow + 2 == inCol) e1.x = 0.f;                               \
            if (inRow + 3 == inCol) e1.y = 0.f;                               \
        }                                                                     \
        rowS2[rt * 2] += e0;                                                  \
        rowS2[rt * 2 + 1] += e1;                                              \
        cs += e0 + e1;                                                        \
    }                                                                         \
    colS[NT] = cs.x + cs.y;                                                   \
    if (isPos && ch == rh) {                                                  \
        int reg = tx - q * 4;                                                 \
        if (reg >= 0 && reg < 4) {                                            \
            float pl = (ACC[NT][reg] + C1_CONST) * LN2_CONST;                 \
            posArr[rowBase + rh * 64 + (NT) * 16 + tx] = pl;                  \
            posArr[colBase + rh * 64 + (NT) * 16 + tx] = pl;                  \
        }                                                                     \
    } }

    stage_panel(Bbase + ((size_t)c0 << 14), shB[0], w, lane);
    int cur = 0;
    for (int ti = 0; ti < n; ti++) {
        int C = c0 + ti;
        __syncthreads();   // drains vmcnt: buf[cur] staged; prior readers of buf[cur^1] done
        if (ti + 1 < n)    // prefetch next panel into the other buffer (drained next iter)
            stage_panel(Bbase + ((size_t)(C + 1) << 14), shB[cur ^ 1], w, lane);
        bool isDiag = (C == diagC), isPos = (C == posC);
        int colBase = C * 128;
        const bf16_t* sb = shB[cur];

        float colS[4];
        bf16x8 bfA[4], bfB[4];
        f32x4 accA[4], accB[4];
        // 2-stage pipeline: MFMA(nt+1) issues before EPI(nt)
        LOADBF(bfA, 0) MFMAS(accA, bfA)
        LOADBF(bfB, 1) MFMAS(accB, bfB)
        EPI(0, accA)
        LOADBF(bfA, 2) MFMAS(accA, bfA)
        EPI(1, accB)
        LOADBF(bfB, 3) MFMAS(accB, bfB)
        EPI(2, accA)
        EPI(3, accB)

        if (!isDiag) {
#pragma unroll
            for (int i = 0; i < 4; i++) {
                colS[i] += __shfl_xor(colS[i], 16, 64);
                colS[i] += __shfl_xor(colS[i], 32, 64);
            }
            if (q == 0) {
                // slot (tri(C,R), rh): unique (rh,col) writer per pair
                float* cdst = colArr + (size_t)(C * (C - 1) / 2) * 256 + rh * 128;
#pragma unroll
                for (int nt = 0; nt < 4; nt++)
                    cdst[ch * 64 + nt * 16 + tx] = colS[nt];
            }
        }
        cur ^= 1;
    }
    // flush rowS: reduce over 16 tx lanes, plain store into [chunk][ch][row]
    float* rowS = (float*)rowS2;   // [rt*4 + reg]
#pragma unroll
    for (int off = 1; off <= 8; off <<= 1)
#pragma unroll
        for (int i = 0; i < 16; i++) rowS[i] += __shfl_xor(rowS[i], off, 16);
    if (tx == 0) {
#pragma unroll
        for (int rt = 0; rt < 4; rt++)
#pragma unroll
            for (int reg = 0; reg < 4; reg++)
                rowDst[ch * 128 + rh * 64 + rt * 16 + q * 4 + reg] =
                    rowS[rt * 4 + reg];
    }
#undef LOADBF
#undef MFMAS
#undef EPI
}

// ================= kernel 3: finalize (reduce partials, 512t + term-split) ====
__global__ __launch_bounds__(512) void fin_k(const float* __restrict__ pos,
                                             const float* __restrict__ posp,
                                             const float* __restrict__ colI,
                                             const float* __restrict__ rowI,
                                             const float* __restrict__ colP,
                                             const float* __restrict__ rowP,
                                             const int* __restrict__ c1,
                                             const int* __restrict__ c2,
                                             float* __restrict__ acc,
                                             float* __restrict__ out) {
    int bx = blockIdx.x, t = threadIdx.x;
    int lane = t & 63, w = t >> 6;
    float va = 0.f, nv = 0.f;
    __shared__ float part[2][2][128];
    if (bx < 128) {
        // ins panel p: S[p*128+r] = sum_ci rowI[p*16+ci][s][r] + sum_{R<p} colI[tri(p,R)][s][r]
        int p = 127 - bx;                 // heaviest (largest p) panels first
        int u = t >> 8, half = (t >> 7) & 1, r = t & 127;
        int cc = 16 - (p >> 3);
        float s0 = 0.f, s1 = 0.f, s2 = 0.f, s3 = 0.f;
        const float* RIp = rowI + (size_t)(p * 16) * 256 + half * 128 + r;
        int ci = u;
        for (; ci + 6 < cc; ci += 8) {
            s0 += RIp[ci * 256];       s1 += RIp[(ci + 2) * 256];
            s2 += RIp[(ci + 4) * 256]; s3 += RIp[(ci + 6) * 256];
        }
        for (; ci < cc; ci += 2) s0 += RIp[ci * 256];
        const float* CIp = colI + (size_t)(p * (p - 1) / 2) * 256 + half * 128 + r;
        int Rq = u;
        for (; Rq + 6 < p; Rq += 8) {
            s0 += CIp[Rq * 256];       s1 += CIp[(Rq + 2) * 256];
            s2 += CIp[(Rq + 4) * 256]; s3 += CIp[(Rq + 6) * 256];
        }
        for (; Rq < p; Rq += 2) s0 += CIp[Rq * 256];
        part[u][half][r] = (s0 + s1) + (s2 + s3);
        __syncthreads();
        if (t < 128) {
            float S = (part[0][0][t] + part[0][1][t]) +
                      (part[1][0][t] + part[1][1][t]);
            va = __logf(S) + 10.0f - pos[p * 128 + t];
        }
    } else {
        // patch batch b: 512 rows, one per thread
        int b = bx - 128;
        int idx = t;                      // 0..511
        int p = idx >> 7, r = idx & 127;
        const float* RPp = rowP + (size_t)((b << 2) + p) * 256 + r;
        float s = RPp[0] + RPp[128];
        const float* CPp = colP + (size_t)(b * 6 + p * (p - 1) / 2) * 256 + r;
        for (int Rq = 0; Rq < p; Rq++) s += CPp[Rq * 256] + CPp[Rq * 256 + 128];
        int cnt = (idx < P) ? c1[b * P + idx] : c2[b * P + idx - P];
        if (cnt != 0) {
            va = __logf(s) + 10.0f - posp[b * NP + idx];
            nv = 1.0f;
        }
    }
#pragma unroll
    for (int off = 32; off >= 1; off >>= 1) {
        va += __shfl_down(va, off, 64);
        nv += __shfl_down(nv, off, 64);
    }
    __shared__ float psum[8], pn[8];
    if (lane == 0) { psum[w] = va; pn[w] = nv; }
    __syncthreads();
    if (t == 0) {
        float sv = 0.f, sn = 0.f;
#pragma unroll
        for (int i = 0; i < 8; i++) { sv += psum[i]; sn += pn[i]; }
        if (bx < 128) {
            atomicAdd(&acc[0], sv);
        } else {
            atomicAdd(&acc[1], sv);
            atomicAdd(&acc[2], sn);
        }
        __threadfence();
        unsigned old = atomicAdd((unsigned*)&acc[3], 1u);
        if (old == NB_FIN - 1) {
            float a0 = atomicAdd(&acc[0], 0.0f);
            float a1 = atomicAdd(&acc[1], 0.0f);
            float a2 = atomicAdd(&acc[2], 0.0f);
            out[0] = a0 * (1.0f / (float)N_INS) + a1 / a2;
        }
    }
}

// ---------------- launch ----------------
extern "C" void kernel_launch(void* const* d_in, const int* in_sizes, int n_in,
                              void* d_out, int out_size, void* d_ws, size_t ws_size,
                              hipStream_t stream) {
    const float* v1i = (const float*)d_in[0];
    const float* v2i = (const float*)d_in[1];
    const float* v1p = (const float*)d_in[2];
    const float* v2p = (const float*)d_in[3];
    const int* c1 = (const int*)d_in[4];
    const int* c2 = (const int*)d_in[5];
    float* ws = (float*)d_ws;
    float* out = (float*)d_out;
    bf16_t* embI = (bf16_t*)((char*)d_ws + EMB_I_BYTE);
    bf16_t* embP = (bf16_t*)((char*)d_ws + EMB_P_BYTE);

    prep_k<<<NB_PREP, 256, 0, stream>>>(v1i, v2i, v1p, v2p, embI, embP, ws);
    gram_k<<<NB_GRAM, 256, 0, stream>>>(embI, embP, ws + WS_POS, ws + WS_PPOS,
                                        ws + WS_CI, ws + WS_RI,
                                        ws + WS_CP, ws + WS_RP);
    fin_k<<<NB_FIN, 512, 0, stream>>>(ws + WS_POS, ws + WS_PPOS, ws + WS_CI,
                                      ws + WS_RI, ws + WS_CP, ws + WS_RP,
                                      c1, c2, ws + WS_ACC, out);
}